// Round 1
// baseline (7332.173 us; speedup 1.0000x reference)
//
#include <hip/hip_runtime.h>
#include <math.h>

#define Mtot 4096   // B*T
#define Dd   512
#define Hh   8
#define DKk  64
#define Tt   1024
#define Ff   2048
#define Ll   4
#define Vv   32000

// ---------------- embedding + sinusoidal PE ----------------
__global__ __launch_bounds__(256) void embed_pe_kernel(const int* __restrict__ x,
                                                       const float* __restrict__ embed,
                                                       float* __restrict__ h) {
    int idx = blockIdx.x * 256 + threadIdx.x;      // [0, Mtot*Dd)
    int d  = idx & (Dd - 1);
    int bt = idx >> 9;                             // Dd = 512 = 2^9
    int t  = bt & (Tt - 1);
    int tok = x[bt];
    float val = (tok == 0) ? 0.0f : embed[(size_t)tok * Dd + d];
    int de = d & ~1;
    float ang = (float)t * expf((float)de * (-9.210340371976184f / (float)Dd)); // ln(10000)
    val += (d & 1) ? cosf(ang) : sinf(ang);
    h[idx] = val;
}

// ---------------- generic tiled fp32 GEMM: C = act(A@B + bias) ----------------
// A [M,K] row-major, B [K,N] row-major, bias [N]. act: 0=none, 1=exact GELU.
__global__ __launch_bounds__(256) void gemm_bias_kernel(const float* __restrict__ A,
                                                        const float* __restrict__ B,
                                                        const float* __restrict__ bias,
                                                        float* __restrict__ C,
                                                        int M, int N, int K, int act) {
    __shared__ float As[16][68];   // [k][m], padded: 68*4B=272B -> 16B aligned rows
    __shared__ float Bs[16][68];   // [k][n]
    int tid = threadIdx.x;
    int tn = tid & 15, tm = tid >> 4;
    int bn = blockIdx.x, bm = blockIdx.y;
    float acc[4][4] = {};
    const float* Ablk = A + (size_t)bm * 64 * K;
    const float* Bblk = B + (size_t)bn * 64;
    for (int k0 = 0; k0 < K; k0 += 16) {
        #pragma unroll
        for (int i = 0; i < 4; i++) {              // A tile 64x16
            int idx = tid + i * 256;
            int r = idx >> 4, c = idx & 15;
            As[c][r] = Ablk[(size_t)r * K + k0 + c];
        }
        #pragma unroll
        for (int i = 0; i < 4; i++) {              // B tile 16x64
            int idx = tid + i * 256;
            int r = idx >> 6, c = idx & 63;
            Bs[r][c] = Bblk[(size_t)(k0 + r) * N + c];
        }
        __syncthreads();
        #pragma unroll
        for (int kk = 0; kk < 16; kk++) {
            float a[4], b[4];
            #pragma unroll
            for (int i = 0; i < 4; i++) a[i] = As[kk][tm * 4 + i];
            #pragma unroll
            for (int j = 0; j < 4; j++) b[j] = Bs[kk][tn * 4 + j];
            #pragma unroll
            for (int i = 0; i < 4; i++)
                #pragma unroll
                for (int j = 0; j < 4; j++)
                    acc[i][j] += a[i] * b[j];
        }
        __syncthreads();
    }
    #pragma unroll
    for (int i = 0; i < 4; i++) {
        int row = bm * 64 + tm * 4 + i;
        #pragma unroll
        for (int j = 0; j < 4; j++) {
            int col = bn * 64 + tn * 4 + j;
            float v = acc[i][j] + bias[col];
            if (act == 1) v = 0.5f * v * (1.0f + erff(v * 0.7071067811865475f));
            C[(size_t)row * N + col] = v;
        }
    }
}

// ---------------- attention: one block per (b, head, q-row) ----------------
__global__ __launch_bounds__(256) void attn_kernel(const float* __restrict__ Q,
                                                   const float* __restrict__ K,
                                                   const float* __restrict__ V,
                                                   float* __restrict__ O) {
    int blk = blockIdx.x;
    int qi = blk & (Tt - 1);
    int hh = (blk >> 10) & (Hh - 1);
    int b  = blk >> 13;
    int tid = threadIdx.x;

    __shared__ float qv[DKk];
    __shared__ float s[Tt];
    __shared__ float red[256];
    __shared__ float opart[4][DKk];

    const float* qrow = Q + ((size_t)(b * Tt + qi)) * Dd + hh * DKk;
    if (tid < DKk) qv[tid] = qrow[tid];
    __syncthreads();

    float lmax = -INFINITY;
    for (int t = tid; t <= qi; t += 256) {
        const float* krow = K + ((size_t)(b * Tt + t)) * Dd + hh * DKk;
        float dot = 0.0f;
        #pragma unroll
        for (int d = 0; d < DKk; d++) dot += qv[d] * krow[d];
        dot *= 0.125f;                      // 1/sqrt(64)
        s[t] = dot;
        lmax = fmaxf(lmax, dot);
    }
    red[tid] = lmax; __syncthreads();
    for (int st = 128; st > 0; st >>= 1) { if (tid < st) red[tid] = fmaxf(red[tid], red[tid + st]); __syncthreads(); }
    float mx = red[0]; __syncthreads();

    float lsum = 0.0f;
    for (int t = tid; t <= qi; t += 256) { float e = expf(s[t] - mx); s[t] = e; lsum += e; }
    red[tid] = lsum; __syncthreads();
    for (int st = 128; st > 0; st >>= 1) { if (tid < st) red[tid] += red[tid + st]; __syncthreads(); }
    float inv = 1.0f / red[0];
    __syncthreads();

    int d = tid & (DKk - 1), chunk = tid >> 6;
    float acc = 0.0f;
    for (int t = chunk; t <= qi; t += 4)
        acc += s[t] * V[((size_t)(b * Tt + t)) * Dd + hh * DKk + d];
    opart[chunk][d] = acc;
    __syncthreads();
    if (tid < DKk) {
        float o = (opart[0][tid] + opart[1][tid] + opart[2][tid] + opart[3][tid]) * inv;
        O[((size_t)(b * Tt + qi)) * Dd + hh * DKk + tid] = o;
    }
}

// ---------------- residual add + LayerNorm (in place on h) ----------------
__global__ __launch_bounds__(256) void ln_kernel(float* __restrict__ h,
                                                 const float* __restrict__ delta,
                                                 const float* __restrict__ gs,
                                                 const float* __restrict__ gb) {
    __shared__ float red[256];
    int row = blockIdx.x, tid = threadIdx.x;
    size_t base = (size_t)row * Dd;
    float x0 = h[base + tid], x1 = h[base + tid + 256];
    if (delta != nullptr) { x0 += delta[base + tid]; x1 += delta[base + tid + 256]; }
    red[tid] = x0 + x1; __syncthreads();
    for (int st = 128; st > 0; st >>= 1) { if (tid < st) red[tid] += red[tid + st]; __syncthreads(); }
    float m = red[0] * (1.0f / Dd); __syncthreads();
    float d0 = x0 - m, d1 = x1 - m;
    red[tid] = d0 * d0 + d1 * d1; __syncthreads();
    for (int st = 128; st > 0; st >>= 1) { if (tid < st) red[tid] += red[tid + st]; __syncthreads(); }
    float r = rsqrtf(red[0] * (1.0f / Dd) + 1e-5f);
    h[base + tid]       = d0 * r * gs[tid]       + gb[tid];
    h[base + tid + 256] = d1 * r * gs[tid + 256] + gb[tid + 256];
}

extern "C" void kernel_launch(void* const* d_in, const int* in_sizes, int n_in,
                              void* d_out, int out_size, void* d_ws, size_t ws_size,
                              hipStream_t stream) {
    const int*   x     = (const int*)  d_in[0];
    const float* embed = (const float*)d_in[1];
    const float* Wq    = (const float*)d_in[2];
    const float* bq    = (const float*)d_in[3];
    const float* Wk    = (const float*)d_in[4];
    const float* bk    = (const float*)d_in[5];
    const float* Wv    = (const float*)d_in[6];
    const float* bv    = (const float*)d_in[7];
    const float* Wo    = (const float*)d_in[8];
    const float* bo    = (const float*)d_in[9];
    const float* ln1_s = (const float*)d_in[10];
    const float* ln1_b = (const float*)d_in[11];
    const float* W1    = (const float*)d_in[12];
    const float* b1    = (const float*)d_in[13];
    const float* W2    = (const float*)d_in[14];
    const float* b2    = (const float*)d_in[15];
    const float* ln2_s = (const float*)d_in[16];
    const float* ln2_b = (const float*)d_in[17];
    const float* lnf_s = (const float*)d_in[18];
    const float* lnf_b = (const float*)d_in[19];
    const float* Wl    = (const float*)d_in[20];
    const float* bl    = (const float*)d_in[21];

    size_t MD = (size_t)Mtot * Dd;
    float* h  = (float*)d_ws;
    float* qb = h  + MD;
    float* kb = qb + MD;
    float* vb = kb + MD;
    float* ob = vb + MD;
    float* pb = ob + MD;
    float* fb = pb + MD;          // Mtot * Ff

    embed_pe_kernel<<<(Mtot * Dd) / 256, 256, 0, stream>>>(x, embed, h);

    for (int l = 0; l < Ll; l++) {
        const float* wq = Wq + (size_t)l * Dd * Dd;
        const float* wk = Wk + (size_t)l * Dd * Dd;
        const float* wv = Wv + (size_t)l * Dd * Dd;
        const float* wo = Wo + (size_t)l * Dd * Dd;
        const float* w1 = W1 + (size_t)l * Dd * Ff;
        const float* w2 = W2 + (size_t)l * Ff * Dd;

        gemm_bias_kernel<<<dim3(Dd / 64, Mtot / 64), 256, 0, stream>>>(h, wq, bq + l * Dd, qb, Mtot, Dd, Dd, 0);
        gemm_bias_kernel<<<dim3(Dd / 64, Mtot / 64), 256, 0, stream>>>(h, wk, bk + l * Dd, kb, Mtot, Dd, Dd, 0);
        gemm_bias_kernel<<<dim3(Dd / 64, Mtot / 64), 256, 0, stream>>>(h, wv, bv + l * Dd, vb, Mtot, Dd, Dd, 0);

        attn_kernel<<<Mtot * Hh, 256, 0, stream>>>(qb, kb, vb, ob);

        gemm_bias_kernel<<<dim3(Dd / 64, Mtot / 64), 256, 0, stream>>>(ob, wo, bo + l * Dd, pb, Mtot, Dd, Dd, 0);
        ln_kernel<<<Mtot, 256, 0, stream>>>(h, pb, ln1_s + l * Dd, ln1_b + l * Dd);

        gemm_bias_kernel<<<dim3(Ff / 64, Mtot / 64), 256, 0, stream>>>(h, w1, b1 + l * Ff, fb, Mtot, Ff, Dd, 1);
        gemm_bias_kernel<<<dim3(Dd / 64, Mtot / 64), 256, 0, stream>>>(fb, w2, b2 + l * Dd, pb, Mtot, Dd, Ff, 0);
        ln_kernel<<<Mtot, 256, 0, stream>>>(h, pb, ln2_s + l * Dd, ln2_b + l * Dd);
    }

    ln_kernel<<<Mtot, 256, 0, stream>>>(h, nullptr, lnf_s, lnf_b);
    gemm_bias_kernel<<<dim3(Vv / 64, Mtot / 64), 256, 0, stream>>>(h, Wl, bl, (float*)d_out, Mtot, Vv, Dd, 0);
}

// Round 2
// 1711.717 us; speedup vs baseline: 4.2835x; 4.2835x over previous
//
#include <hip/hip_runtime.h>
#include <math.h>

#define Mtot 4096   // B*T
#define Dd   512
#define Hh   8
#define DKk  64
#define TT   1024
#define Ff   2048
#define Ll   4
#define Vv   32000

typedef __attribute__((ext_vector_type(8))) short bf16x8;
typedef __attribute__((ext_vector_type(4))) float f32x4;
typedef unsigned short u16;

__device__ __forceinline__ u16 f2b(float f) {
    union { float f; unsigned u; } x; x.f = f;
    unsigned r = x.u + 0x7fffu + ((x.u >> 16) & 1u);
    return (u16)(r >> 16);
}

typedef const __attribute__((address_space(1))) unsigned int* gp_t;
typedef __attribute__((address_space(3))) unsigned int* lp_t;
#define GLOAD_LDS16(g, l) __builtin_amdgcn_global_load_lds((gp_t)(const void*)(g), (lp_t)(void*)(l), 16, 0, 0)

// ---------------- embedding + sinusoidal PE (fp32 h + bf16 mirror) ----------------
__global__ __launch_bounds__(256) void embed_pe_kernel(const int* __restrict__ x,
                                                       const float* __restrict__ embed,
                                                       float* __restrict__ h,
                                                       u16* __restrict__ hb) {
    int idx = blockIdx.x * 256 + threadIdx.x;
    int d  = idx & (Dd - 1);
    int bt = idx >> 9;
    int t  = bt & (TT - 1);
    int tok = x[bt];
    float val = (tok == 0) ? 0.0f : embed[(size_t)tok * Dd + d];
    int de = d & ~1;
    float ang = (float)t * expf((float)de * (-9.210340371976184f / (float)Dd));
    val += (d & 1) ? cosf(ang) : sinf(ang);
    h[idx] = val;
    hb[idx] = f2b(val);
}

// ---------------- weight transpose + bf16 convert: in[K][N] f32 -> out[N][K] bf16 ----------------
__global__ __launch_bounds__(256) void transpose_kernel(const float* __restrict__ in,
                                                        u16* __restrict__ out,
                                                        int K, int N) {
    __shared__ float t[32][33];
    int n0 = blockIdx.x * 32, k0 = blockIdx.y * 32;
    int tid = threadIdx.x;
    int c = tid & 31, r = tid >> 5;   // 8 rows per pass
    #pragma unroll
    for (int i = 0; i < 4; i++)
        t[r + i * 8][c] = in[(size_t)(k0 + r + i * 8) * N + n0 + c];
    __syncthreads();
    #pragma unroll
    for (int i = 0; i < 4; i++)
        out[(size_t)(n0 + r + i * 8) * K + k0 + c] = f2b(t[c][r + i * 8]);
}

// ---------------- pack QKV biases: [L][1536] ----------------
__global__ __launch_bounds__(256) void biaspack_kernel(const float* __restrict__ bq,
                                                       const float* __restrict__ bk,
                                                       const float* __restrict__ bv,
                                                       float* __restrict__ bqkv) {
    int idx = blockIdx.x * 256 + threadIdx.x;   // L*1536
    int l = idx / 1536, j = idx - l * 1536;
    float v = (j < 512) ? bq[l * 512 + j] : (j < 1024) ? bk[l * 512 + j - 512] : bv[l * 512 + j - 1024];
    bqkv[idx] = v;
}

// ---------------- bf16 MFMA GEMM (m97 structure): C = act(A@B + bias) ----------------
// A [M][K] bf16, BT [N][K] bf16 (pre-transposed). 128x128 tile, BK=32, 4 waves.
// ACT: 0=none, 1=exact GELU. OUTB: 1 -> bf16 out, 0 -> f32 out.
template<int ACT, int OUTB>
__global__ __launch_bounds__(256) void mfma_gemm(const u16* __restrict__ A,
                                                 const u16* __restrict__ BT,
                                                 const float* __restrict__ bias,
                                                 float* __restrict__ outF,
                                                 u16* __restrict__ outB,
                                                 int M, int N, int K) {
    __shared__ u16 As[128 * 32];
    __shared__ u16 Bs[128 * 32];
    int tid = threadIdx.x;
    int lane = tid & 63, w = tid >> 6;
    int bn = blockIdx.x, bm = blockIdx.y;
    int wr = w >> 1, wc = w & 1;
    int fr = lane & 15, fq = lane >> 4;
    f32x4 acc[4][4] = {};

    const u16* Ab = A + (size_t)(bm * 128 + w * 32 + (lane >> 2)) * K + (lane & 3) * 8;
    const u16* Bb = BT + (size_t)(bn * 128 + w * 32 + (lane >> 2)) * K + (lane & 3) * 8;
    u16* lA0 = &As[(w * 32) * 32];
    u16* lA1 = &As[(w * 32 + 16) * 32];
    u16* lB0 = &Bs[(w * 32) * 32];
    u16* lB1 = &Bs[(w * 32 + 16) * 32];

    for (int k0 = 0; k0 < K; k0 += 32) {
        GLOAD_LDS16(Ab + k0,          lA0);
        GLOAD_LDS16(Ab + 16 * K + k0, lA1);
        GLOAD_LDS16(Bb + k0,          lB0);
        GLOAD_LDS16(Bb + 16 * K + k0, lB1);
        __syncthreads();
        bf16x8 a[4], b[4];
        #pragma unroll
        for (int m = 0; m < 4; m++) a[m] = *(const bf16x8*)&As[(wr * 64 + m * 16 + fr) * 32 + fq * 8];
        #pragma unroll
        for (int n = 0; n < 4; n++) b[n] = *(const bf16x8*)&Bs[(wc * 64 + n * 16 + fr) * 32 + fq * 8];
        #pragma unroll
        for (int m = 0; m < 4; m++)
            #pragma unroll
            for (int n = 0; n < 4; n++)
                acc[m][n] = __builtin_amdgcn_mfma_f32_16x16x32_bf16(a[m], b[n], acc[m][n], 0, 0, 0);
        __syncthreads();
    }

    #pragma unroll
    for (int m = 0; m < 4; m++) {
        #pragma unroll
        for (int n = 0; n < 4; n++) {
            int col = bn * 128 + wc * 64 + n * 16 + fr;
            float bs = bias[col];
            #pragma unroll
            for (int r = 0; r < 4; r++) {
                int row = bm * 128 + wr * 64 + m * 16 + fq * 4 + r;
                float v = acc[m][n][r] + bs;
                if (ACT == 1) v = 0.5f * v * (1.0f + erff(v * 0.7071067811865475f));
                if (OUTB) outB[(size_t)row * N + col] = f2b(v);
                else      outF[(size_t)row * N + col] = v;
            }
        }
    }
}

// ---------------- flash attention, fp32, Q-tile 64 x KV-tile 32 ----------------
// qkv [M][1536] f32 (q|k|v per row). out ob [M][512] bf16.
__global__ __launch_bounds__(256) void attn_flash(const float* __restrict__ qkv,
                                                  u16* __restrict__ ob) {
    int qt = blockIdx.x, hh = blockIdx.y, b = blockIdx.z;
    __shared__ float qs[64][68];
    __shared__ float ks[32][68];
    __shared__ float vs[32][68];
    __shared__ float sS[64][36];
    __shared__ float mrow[64], lrow[64], fac[64];
    int tid = threadIdx.x;
    int q0 = qt * 64;

    {   // load Q tile [64][64]
        int r = tid >> 2, c0 = (tid & 3) * 4;
        size_t base = ((size_t)(b * TT + q0 + r)) * 1536 + hh * 64;
        #pragma unroll
        for (int j = 0; j < 4; j++) {
            int c = c0 + j * 16;
            *(f32x4*)&qs[r][c] = *(const f32x4*)&qkv[base + c];
        }
    }
    if (tid < 64) { mrow[tid] = -INFINITY; lrow[tid] = 0.0f; }

    float o[4][4] = {};
    int tq4 = tid >> 4;    // q rows tq4*4+i
    int tk2 = tid & 15;    // S phase: k cols tk2*2+j ; PV phase: d cols tk2*4+j
    int nkt = qt * 2 + 2;

    for (int kt = 0; kt < nkt; kt++) {
        __syncthreads();   // prev PV done before restaging ks/vs
        {   // stage K,V tile [32][64]
            int r = tid >> 3, c = (tid & 7) * 8;
            size_t baseK = ((size_t)(b * TT + kt * 32 + r)) * 1536 + 512 + hh * 64 + c;
            *(f32x4*)&ks[r][c]     = *(const f32x4*)&qkv[baseK];
            *(f32x4*)&ks[r][c + 4] = *(const f32x4*)&qkv[baseK + 4];
            *(f32x4*)&vs[r][c]     = *(const f32x4*)&qkv[baseK + 512];
            *(f32x4*)&vs[r][c + 4] = *(const f32x4*)&qkv[baseK + 516];
        }
        __syncthreads();

        // S = Q K^T * scale, causal mask
        float sv[4][2] = {};
        #pragma unroll
        for (int d4 = 0; d4 < 16; d4++) {
            f32x4 kv0 = *(f32x4*)&ks[tk2 * 2][d4 * 4];
            f32x4 kv1 = *(f32x4*)&ks[tk2 * 2 + 1][d4 * 4];
            #pragma unroll
            for (int i = 0; i < 4; i++) {
                f32x4 qv = *(f32x4*)&qs[tq4 * 4 + i][d4 * 4];
                #pragma unroll
                for (int e = 0; e < 4; e++) { sv[i][0] += qv[e] * kv0[e]; sv[i][1] += qv[e] * kv1[e]; }
            }
        }
        #pragma unroll
        for (int i = 0; i < 4; i++) {
            int q = tq4 * 4 + i, qg = q0 + q;
            #pragma unroll
            for (int j = 0; j < 2; j++) {
                int k = tk2 * 2 + j, kg = kt * 32 + k;
                float s = sv[i][j] * 0.125f;
                if (kg > qg) s = -1e30f;
                sS[q][k] = s;
            }
        }
        __syncthreads();

        // online softmax row update (64 threads, one per q row)
        if (tid < 64) {
            float mold = mrow[tid];
            float tm = -1e30f;
            #pragma unroll 8
            for (int k = 0; k < 32; k++) tm = fmaxf(tm, sS[tid][k]);
            float mnew = fmaxf(mold, tm);
            float f = __expf(mold - mnew);   // exp(-inf)=0 on first tile
            float sum = 0.0f;
            #pragma unroll 8
            for (int k = 0; k < 32; k++) {
                float e = __expf(sS[tid][k] - mnew);
                sS[tid][k] = e;
                sum += e;
            }
            lrow[tid] = lrow[tid] * f + sum;
            mrow[tid] = mnew;
            fac[tid] = f;
        }
        __syncthreads();

        // O = O*fac + P V
        #pragma unroll
        for (int i = 0; i < 4; i++) {
            float f = fac[tq4 * 4 + i];
            #pragma unroll
            for (int j = 0; j < 4; j++) o[i][j] *= f;
        }
        #pragma unroll 4
        for (int k = 0; k < 32; k++) {
            f32x4 vv = *(f32x4*)&vs[k][tk2 * 4];
            #pragma unroll
            for (int i = 0; i < 4; i++) {
                float p = sS[tq4 * 4 + i][k];
                #pragma unroll
                for (int j = 0; j < 4; j++) o[i][j] += p * vv[j];
            }
        }
    }

    #pragma unroll
    for (int i = 0; i < 4; i++) {
        int q = tq4 * 4 + i;
        float inv = 1.0f / lrow[q];
        size_t orow = ((size_t)(b * TT + q0 + q)) * Dd + hh * DKk + tk2 * 4;
        #pragma unroll
        for (int j = 0; j < 4; j++) ob[orow + j] = f2b(o[i][j] * inv);
    }
}

// ---------------- residual add + LayerNorm (in place on h, bf16 mirror) ----------------
__global__ __launch_bounds__(256) void ln_kernel(float* __restrict__ h,
                                                 const float* __restrict__ delta,
                                                 const float* __restrict__ gs,
                                                 const float* __restrict__ gb,
                                                 u16* __restrict__ hb) {
    __shared__ float red[256];
    int row = blockIdx.x, tid = threadIdx.x;
    size_t base = (size_t)row * Dd;
    float x0 = h[base + tid], x1 = h[base + tid + 256];
    if (delta != nullptr) { x0 += delta[base + tid]; x1 += delta[base + tid + 256]; }
    red[tid] = x0 + x1; __syncthreads();
    for (int st = 128; st > 0; st >>= 1) { if (tid < st) red[tid] += red[tid + st]; __syncthreads(); }
    float m = red[0] * (1.0f / Dd); __syncthreads();
    float d0 = x0 - m, d1 = x1 - m;
    red[tid] = d0 * d0 + d1 * d1; __syncthreads();
    for (int st = 128; st > 0; st >>= 1) { if (tid < st) red[tid] += red[tid + st]; __syncthreads(); }
    float r = rsqrtf(red[0] * (1.0f / Dd) + 1e-5f);
    float y0 = d0 * r * gs[tid] + gb[tid];
    float y1 = d1 * r * gs[tid + 256] + gb[tid + 256];
    h[base + tid] = y0;         h[base + tid + 256] = y1;
    hb[base + tid] = f2b(y0);   hb[base + tid + 256] = f2b(y1);
}

extern "C" void kernel_launch(void* const* d_in, const int* in_sizes, int n_in,
                              void* d_out, int out_size, void* d_ws, size_t ws_size,
                              hipStream_t stream) {
    const int*   x     = (const int*)  d_in[0];
    const float* embed = (const float*)d_in[1];
    const float* Wq    = (const float*)d_in[2];
    const float* bq    = (const float*)d_in[3];
    const float* Wk    = (const float*)d_in[4];
    const float* bk    = (const float*)d_in[5];
    const float* Wv    = (const float*)d_in[6];
    const float* bv    = (const float*)d_in[7];
    const float* Wo    = (const float*)d_in[8];
    const float* bo    = (const float*)d_in[9];
    const float* ln1_s = (const float*)d_in[10];
    const float* ln1_b = (const float*)d_in[11];
    const float* W1    = (const float*)d_in[12];
    const float* b1    = (const float*)d_in[13];
    const float* W2    = (const float*)d_in[14];
    const float* b2    = (const float*)d_in[15];
    const float* ln2_s = (const float*)d_in[16];
    const float* ln2_b = (const float*)d_in[17];
    const float* lnf_s = (const float*)d_in[18];
    const float* lnf_b = (const float*)d_in[19];
    const float* Wl    = (const float*)d_in[20];
    const float* bl    = (const float*)d_in[21];

    // ---- workspace layout ----
    char* wp = (char*)d_ws;
    float* h    = (float*)wp;  wp += (size_t)Mtot * Dd * 4;       //  8 MB
    float* qkvb = (float*)wp;  wp += (size_t)Mtot * 1536 * 4;     // 25 MB
    float* pb   = (float*)wp;  wp += (size_t)Mtot * Dd * 4;       //  8 MB
    u16*   hb   = (u16*)wp;    wp += (size_t)Mtot * Dd * 2;       //  4 MB
    u16*   obb  = (u16*)wp;    wp += (size_t)Mtot * Dd * 2;       //  4 MB
    u16*   fbb  = (u16*)wp;    wp += (size_t)Mtot * Ff * 2;       // 16 MB
    u16*   WlT  = (u16*)wp;    wp += (size_t)Vv * Dd * 2;         // 33 MB
    float* bqkv = (float*)wp;  wp += (size_t)Ll * 1536 * 4;       // 24 KB

    // ---- transient layer weights in d_out (dead before final logits GEMM writes it) ----
    char* op = (char*)d_out;
    u16* WqkvT = (u16*)op;  op += (size_t)Ll * 1536 * Dd * 2;     // 6.3 MB
    u16* WoT   = (u16*)op;  op += (size_t)Ll * Dd * Dd * 2;       // 2.1 MB
    u16* W1T   = (u16*)op;  op += (size_t)Ll * Ff * Dd * 2;       // 8.4 MB
    u16* W2T   = (u16*)op;  op += (size_t)Ll * Dd * Ff * 2;       // 8.4 MB

    // ---- weight prep ----
    for (int l = 0; l < Ll; l++) {
        u16* wt = WqkvT + (size_t)l * 1536 * Dd;
        transpose_kernel<<<dim3(16, 16), 256, 0, stream>>>(Wq + (size_t)l * Dd * Dd, wt,               Dd, Dd);
        transpose_kernel<<<dim3(16, 16), 256, 0, stream>>>(Wk + (size_t)l * Dd * Dd, wt + 512 * Dd,    Dd, Dd);
        transpose_kernel<<<dim3(16, 16), 256, 0, stream>>>(Wv + (size_t)l * Dd * Dd, wt + 1024 * Dd,   Dd, Dd);
        transpose_kernel<<<dim3(16, 16), 256, 0, stream>>>(Wo + (size_t)l * Dd * Dd, WoT + (size_t)l * Dd * Dd, Dd, Dd);
        transpose_kernel<<<dim3(64, 16), 256, 0, stream>>>(W1 + (size_t)l * Dd * Ff, W1T + (size_t)l * Ff * Dd, Dd, Ff);
        transpose_kernel<<<dim3(16, 64), 256, 0, stream>>>(W2 + (size_t)l * Ff * Dd, W2T + (size_t)l * Dd * Ff, Ff, Dd);
    }
    transpose_kernel<<<dim3(1000, 16), 256, 0, stream>>>(Wl, WlT, Dd, Vv);
    biaspack_kernel<<<24, 256, 0, stream>>>(bq, bk, bv, bqkv);

    embed_pe_kernel<<<(Mtot * Dd) / 256, 256, 0, stream>>>(x, embed, h, hb);

    for (int l = 0; l < Ll; l++) {
        mfma_gemm<0, 0><<<dim3(1536 / 128, Mtot / 128), 256, 0, stream>>>(
            hb, WqkvT + (size_t)l * 1536 * Dd, bqkv + l * 1536, qkvb, nullptr, Mtot, 1536, Dd);
        attn_flash<<<dim3(16, 8, 4), 256, 0, stream>>>(qkvb, obb);
        mfma_gemm<0, 0><<<dim3(Dd / 128, Mtot / 128), 256, 0, stream>>>(
            obb, WoT + (size_t)l * Dd * Dd, bo + l * Dd, pb, nullptr, Mtot, Dd, Dd);
        ln_kernel<<<Mtot, 256, 0, stream>>>(h, pb, ln1_s + l * Dd, ln1_b + l * Dd, hb);
        mfma_gemm<1, 1><<<dim3(Ff / 128, Mtot / 128), 256, 0, stream>>>(
            hb, W1T + (size_t)l * Ff * Dd, b1 + l * Ff, nullptr, fbb, Mtot, Ff, Dd);
        mfma_gemm<0, 0><<<dim3(Dd / 128, Mtot / 128), 256, 0, stream>>>(
            fbb, W2T + (size_t)l * Dd * Ff, b2 + l * Dd, pb, nullptr, Mtot, Dd, Ff);
        ln_kernel<<<Mtot, 256, 0, stream>>>(h, pb, ln2_s + l * Dd, ln2_b + l * Dd, hb);
    }

    ln_kernel<<<Mtot, 256, 0, stream>>>(h, nullptr, lnf_s, lnf_b, hb);
    mfma_gemm<0, 0><<<dim3(Vv / 128, Mtot / 128), 256, 0, stream>>>(
        hb, WlT, bl, (float*)d_out, nullptr, Mtot, Vv, Dd);
}

// Round 3
// 898.139 us; speedup vs baseline: 8.1637x; 1.9058x over previous
//
#include <hip/hip_runtime.h>
#include <math.h>

#define Mtot 4096   // B*T
#define Dd   512
#define Hh   8
#define DKk  64
#define TT   1024
#define Ff   2048
#define Ll   4
#define Vv   32000

typedef __attribute__((ext_vector_type(8))) short bf16x8;
typedef __attribute__((ext_vector_type(4))) float f32x4;
typedef unsigned short u16;

__device__ __forceinline__ u16 f2b(float f) {
    union { float f; unsigned u; } x; x.f = f;
    unsigned r = x.u + 0x7fffu + ((x.u >> 16) & 1u);
    return (u16)(r >> 16);
}

typedef const __attribute__((address_space(1))) unsigned int* gp_t;
typedef __attribute__((address_space(3))) unsigned int* lp_t;
#define GLOAD_LDS16(g, l) __builtin_amdgcn_global_load_lds((gp_t)(const void*)(g), (lp_t)(void*)(l), 16, 0, 0)

// LDS swizzles (u16-index space; rows are 64 bf16 = 128 B)
#define SWZ(row, c)  ((c) ^ (((row) & 7) << 3))
#define VSWZ(d, c)   ((c) ^ ((((d) ^ ((d) >> 3)) & 7) << 3))

// ---------------- embedding + sinusoidal PE (fp32 h + bf16 mirror) ----------------
__global__ __launch_bounds__(256) void embed_pe_kernel(const int* __restrict__ x,
                                                       const float* __restrict__ embed,
                                                       float* __restrict__ h,
                                                       u16* __restrict__ hb) {
    int idx = blockIdx.x * 256 + threadIdx.x;
    int d  = idx & (Dd - 1);
    int bt = idx >> 9;
    int t  = bt & (TT - 1);
    int tok = x[bt];
    float val = (tok == 0) ? 0.0f : embed[(size_t)tok * Dd + d];
    int de = d & ~1;
    float ang = (float)t * expf((float)de * (-9.210340371976184f / (float)Dd));
    val += (d & 1) ? cosf(ang) : sinf(ang);
    h[idx] = val;
    hb[idx] = f2b(val);
}

// ---------------- ALL weight transposes in one kernel: src[K][N] f32 -> dst[N][K] bf16 ----------------
__global__ __launch_bounds__(256) void transpose_all(const float* __restrict__ Wq, const float* __restrict__ Wk,
                                                     const float* __restrict__ Wv, const float* __restrict__ Wo,
                                                     const float* __restrict__ W1, const float* __restrict__ W2,
                                                     const float* __restrict__ Wl,
                                                     u16* __restrict__ WqkvT, u16* __restrict__ WoT,
                                                     u16* __restrict__ W1T, u16* __restrict__ W2T,
                                                     u16* __restrict__ WlT) {
    __shared__ float t[32][33];
    int id = blockIdx.x;
    const float* src; u16* dst; int K, N, tx, ty;
    if (id < 12288) {
        int l = id / 3072, r = id - l * 3072;
        if (r < 768) {
            int which = r >> 8, t2 = r & 255;
            src = (which == 0 ? Wq : which == 1 ? Wk : Wv) + (size_t)l * 262144;
            dst = WqkvT + (size_t)l * 786432 + (size_t)which * 262144;
            K = 512; N = 512; ty = t2 >> 4; tx = t2 & 15;
        } else if (r < 1024) {
            int t2 = r - 768;
            src = Wo + (size_t)l * 262144; dst = WoT + (size_t)l * 262144;
            K = 512; N = 512; ty = t2 >> 4; tx = t2 & 15;
        } else if (r < 2048) {
            int t2 = r - 1024;
            src = W1 + (size_t)l * 1048576; dst = W1T + (size_t)l * 1048576;
            K = 512; N = 2048; ty = t2 >> 6; tx = t2 & 63;
        } else {
            int t2 = r - 2048;
            src = W2 + (size_t)l * 1048576; dst = W2T + (size_t)l * 1048576;
            K = 2048; N = 512; ty = t2 >> 4; tx = t2 & 15;
        }
    } else {
        int t2 = id - 12288;
        src = Wl; dst = WlT; K = 512; N = 32000;
        ty = t2 / 1000; tx = t2 - ty * 1000;
    }
    int n0 = tx * 32, k0 = ty * 32;
    int tid = threadIdx.x, c = tid & 31, rr = tid >> 5;
    #pragma unroll
    for (int i = 0; i < 4; i++)
        t[rr + i * 8][c] = src[(size_t)(k0 + rr + i * 8) * N + n0 + c];
    __syncthreads();
    #pragma unroll
    for (int i = 0; i < 4; i++)
        dst[(size_t)(n0 + rr + i * 8) * K + k0 + c] = f2b(t[c][rr + i * 8]);
}

// ---------------- pack QKV biases: [L][1536] ----------------
__global__ __launch_bounds__(256) void biaspack_kernel(const float* __restrict__ bq,
                                                       const float* __restrict__ bk,
                                                       const float* __restrict__ bv,
                                                       float* __restrict__ bqkv) {
    int idx = blockIdx.x * 256 + threadIdx.x;
    int l = idx / 1536, j = idx - l * 1536;
    float v = (j < 512) ? bq[l * 512 + j] : (j < 1024) ? bk[l * 512 + j - 512] : bv[l * 512 + j - 1024];
    bqkv[idx] = v;
}

// ---------------- bf16 MFMA GEMM (m97 structure + XCD swizzle) ----------------
// A [M][K] bf16, BT [N][K] bf16. 128x128 tile, BK=32, 4 waves. grid flat = (N/128)*(M/128), %8==0.
template<int ACT, int OUTB>
__global__ __launch_bounds__(256) void mfma_gemm(const u16* __restrict__ A,
                                                 const u16* __restrict__ BT,
                                                 const float* __restrict__ bias,
                                                 float* __restrict__ outF,
                                                 u16* __restrict__ outB,
                                                 int M, int N, int K, int gx) {
    __shared__ __align__(16) u16 As[128 * 32];
    __shared__ __align__(16) u16 Bs[128 * 32];
    int nwg = gridDim.x;
    int flat = blockIdx.x;
    int wg = (flat & 7) * (nwg >> 3) + (flat >> 3);   // bijective XCD swizzle (nwg%8==0)
    int bm = wg / gx, bn = wg - bm * gx;
    int tid = threadIdx.x;
    int lane = tid & 63, w = tid >> 6;
    int wr = w >> 1, wc = w & 1;
    int fr = lane & 15, fq = lane >> 4;
    f32x4 acc[4][4] = {};

    const u16* Ab = A + (size_t)(bm * 128 + w * 32 + (lane >> 2)) * K + (lane & 3) * 8;
    const u16* Bb = BT + (size_t)(bn * 128 + w * 32 + (lane >> 2)) * K + (lane & 3) * 8;
    u16* lA0 = &As[(w * 32) * 32];
    u16* lA1 = &As[(w * 32 + 16) * 32];
    u16* lB0 = &Bs[(w * 32) * 32];
    u16* lB1 = &Bs[(w * 32 + 16) * 32];

    for (int k0 = 0; k0 < K; k0 += 32) {
        GLOAD_LDS16(Ab + k0,          lA0);
        GLOAD_LDS16(Ab + 16 * K + k0, lA1);
        GLOAD_LDS16(Bb + k0,          lB0);
        GLOAD_LDS16(Bb + 16 * K + k0, lB1);
        __syncthreads();
        bf16x8 a[4], b[4];
        #pragma unroll
        for (int m = 0; m < 4; m++) a[m] = *(const bf16x8*)&As[(wr * 64 + m * 16 + fr) * 32 + fq * 8];
        #pragma unroll
        for (int n = 0; n < 4; n++) b[n] = *(const bf16x8*)&Bs[(wc * 64 + n * 16 + fr) * 32 + fq * 8];
        __builtin_amdgcn_s_setprio(1);
        #pragma unroll
        for (int m = 0; m < 4; m++)
            #pragma unroll
            for (int n = 0; n < 4; n++)
                acc[m][n] = __builtin_amdgcn_mfma_f32_16x16x32_bf16(a[m], b[n], acc[m][n], 0, 0, 0);
        __builtin_amdgcn_s_setprio(0);
        __syncthreads();
    }

    #pragma unroll
    for (int m = 0; m < 4; m++) {
        #pragma unroll
        for (int n = 0; n < 4; n++) {
            int col = bn * 128 + wc * 64 + n * 16 + fr;
            float bs = bias[col];
            #pragma unroll
            for (int r = 0; r < 4; r++) {
                int row = bm * 128 + wr * 64 + m * 16 + fq * 4 + r;
                float v = acc[m][n][r] + bs;
                if (ACT == 1) v = 0.5f * v * (1.0f + erff(v * 0.7071067811865475f));
                if (OUTB) outB[(size_t)row * N + col] = f2b(v);
                else      outF[(size_t)row * N + col] = v;
            }
        }
    }
}

// ---------------- MFMA flash attention: QBLK=64 (4 waves x 16 rows), KVBLK=64 ----------------
// qkv [M][1536] bf16 (q|k|v). ob [M][512] bf16.
__global__ __launch_bounds__(256) void attn_mfma(const u16* __restrict__ qkv,
                                                 u16* __restrict__ ob) {
    int qt = (int)gridDim.x - 1 - (int)blockIdx.x;   // heavy blocks first
    int hh = blockIdx.y, b = blockIdx.z;
    __shared__ __align__(16) u16 Qs[64 * 64];
    __shared__ __align__(16) u16 Ks[64 * 64];
    __shared__ __align__(16) u16 Vt[64 * 64];
    __shared__ __align__(16) u16 Ps[4][16 * 64];
    int tid = threadIdx.x;
    int lane = tid & 63, w = tid >> 6;
    int fr = lane & 15, fq = lane >> 4;
    int q0 = qt * 64;

    {   // stage Q [64][64] swizzled
        int r = tid >> 2, c0 = (tid & 3) * 16;
        const u16* src = qkv + ((size_t)(b * TT + q0 + r)) * 1536 + hh * 64 + c0;
        bf16x8 v0 = *(const bf16x8*)src;
        bf16x8 v1 = *(const bf16x8*)(src + 8);
        *(bf16x8*)&Qs[r * 64 + SWZ(r, c0)]     = v0;
        *(bf16x8*)&Qs[r * 64 + SWZ(r, c0 + 8)] = v1;
    }
    __syncthreads();
    bf16x8 aq0 = *(const bf16x8*)&Qs[(w * 16 + fr) * 64 + SWZ(w * 16 + fr, fq * 8)];
    bf16x8 aq1 = *(const bf16x8*)&Qs[(w * 16 + fr) * 64 + SWZ(w * 16 + fr, 32 + fq * 8)];

    f32x4 oa[4] = {};
    float mreg[4], lreg[4];
    #pragma unroll
    for (int i = 0; i < 4; i++) { mreg[i] = -1e30f; lreg[i] = 0.0f; }

    for (int kt = 0; kt <= qt; kt++) {
        __syncthreads();   // prev tile fully consumed
        {   // stage K rows + V transposed
            int r = tid >> 2, c0 = (tid & 3) * 16;
            const u16* srcK = qkv + ((size_t)(b * TT + kt * 64 + r)) * 1536 + 512 + hh * 64 + c0;
            bf16x8 k0v = *(const bf16x8*)srcK;
            bf16x8 k1v = *(const bf16x8*)(srcK + 8);
            *(bf16x8*)&Ks[r * 64 + SWZ(r, c0)]     = k0v;
            *(bf16x8*)&Ks[r * 64 + SWZ(r, c0 + 8)] = k1v;
            const u16* srcV = srcK + 512;
            bf16x8 vv0 = *(const bf16x8*)srcV;
            bf16x8 vv1 = *(const bf16x8*)(srcV + 8);
            #pragma unroll
            for (int j = 0; j < 8; j++) {
                int d0 = c0 + j, d1 = c0 + 8 + j;
                Vt[d0 * 64 + VSWZ(d0, r)] = (u16)vv0[j];
                Vt[d1 * 64 + VSWZ(d1, r)] = (u16)vv1[j];
            }
        }
        __syncthreads();

        // S = Q K^T  (per wave: 16 q-rows x 64 t-cols)
        f32x4 sa[4] = {};
        __builtin_amdgcn_s_setprio(1);
        #pragma unroll
        for (int nt = 0; nt < 4; nt++) {
            int krow = nt * 16 + fr;
            bf16x8 b0 = *(const bf16x8*)&Ks[krow * 64 + SWZ(krow, fq * 8)];
            bf16x8 b1 = *(const bf16x8*)&Ks[krow * 64 + SWZ(krow, 32 + fq * 8)];
            sa[nt] = __builtin_amdgcn_mfma_f32_16x16x32_bf16(aq0, b0, sa[nt], 0, 0, 0);
            sa[nt] = __builtin_amdgcn_mfma_f32_16x16x32_bf16(aq1, b1, sa[nt], 0, 0, 0);
        }
        __builtin_amdgcn_s_setprio(0);

        // scale + causal mask; lane holds q rows fq*4+i, t col nt*16+fr
        float p[4][4];
        int qg = w * 16 + fq * 4;          // q within block
        bool diag = (kt == qt);
        #pragma unroll
        for (int nt = 0; nt < 4; nt++)
            #pragma unroll
            for (int i = 0; i < 4; i++) {
                float s = sa[nt][i] * 0.125f;
                if (diag && (nt * 16 + fr > qg + i)) s = -1e30f;
                p[nt][i] = s;
            }

        float mnew[4], fscale[4];
        #pragma unroll
        for (int i = 0; i < 4; i++) {
            float v = fmaxf(fmaxf(p[0][i], p[1][i]), fmaxf(p[2][i], p[3][i]));
            v = fmaxf(v, __shfl_xor(v, 1));
            v = fmaxf(v, __shfl_xor(v, 2));
            v = fmaxf(v, __shfl_xor(v, 4));
            v = fmaxf(v, __shfl_xor(v, 8));
            mnew[i] = fmaxf(mreg[i], v);
            fscale[i] = __expf(mreg[i] - mnew[i]);
            mreg[i] = mnew[i];
        }
        #pragma unroll
        for (int i = 0; i < 4; i++) {
            float sum = 0.f;
            #pragma unroll
            for (int nt = 0; nt < 4; nt++) {
                float e = __expf(p[nt][i] - mnew[i]);
                p[nt][i] = e;
                sum += e;
            }
            sum += __shfl_xor(sum, 1);
            sum += __shfl_xor(sum, 2);
            sum += __shfl_xor(sum, 4);
            sum += __shfl_xor(sum, 8);
            lreg[i] = lreg[i] * fscale[i] + sum;
        }
        #pragma unroll
        for (int nn = 0; nn < 4; nn++)
            #pragma unroll
            for (int i = 0; i < 4; i++)
                oa[nn][i] *= fscale[i];

        // P -> bf16 LDS (per-wave region, no barrier needed)
        u16* ps = &Ps[w][0];
        #pragma unroll
        for (int nt = 0; nt < 4; nt++)
            #pragma unroll
            for (int i = 0; i < 4; i++) {
                int row = fq * 4 + i, col = nt * 16 + fr;
                ps[row * 64 + SWZ(row, col)] = f2b(p[nt][i]);
            }
        bf16x8 pa0 = *(const bf16x8*)&ps[fr * 64 + SWZ(fr, fq * 8)];
        bf16x8 pa1 = *(const bf16x8*)&ps[fr * 64 + SWZ(fr, 32 + fq * 8)];
        __builtin_amdgcn_s_setprio(1);
        #pragma unroll
        for (int nn = 0; nn < 4; nn++) {
            int drow = nn * 16 + fr;
            bf16x8 vb0 = *(const bf16x8*)&Vt[drow * 64 + VSWZ(drow, fq * 8)];
            bf16x8 vb1 = *(const bf16x8*)&Vt[drow * 64 + VSWZ(drow, 32 + fq * 8)];
            oa[nn] = __builtin_amdgcn_mfma_f32_16x16x32_bf16(pa0, vb0, oa[nn], 0, 0, 0);
            oa[nn] = __builtin_amdgcn_mfma_f32_16x16x32_bf16(pa1, vb1, oa[nn], 0, 0, 0);
        }
        __builtin_amdgcn_s_setprio(0);
    }

    #pragma unroll
    for (int i = 0; i < 4; i++) {
        float inv = 1.0f / lreg[i];
        size_t row = (size_t)(b * TT + q0 + w * 16 + fq * 4 + i) * Dd + hh * 64;
        #pragma unroll
        for (int nn = 0; nn < 4; nn++)
            ob[row + nn * 16 + fr] = f2b(oa[nn][i] * inv);
    }
}

// ---------------- residual add + LayerNorm (in place on h, bf16 mirror) ----------------
__global__ __launch_bounds__(256) void ln_kernel(float* __restrict__ h,
                                                 const float* __restrict__ delta,
                                                 const float* __restrict__ gs,
                                                 const float* __restrict__ gb,
                                                 u16* __restrict__ hb) {
    __shared__ float red[256];
    int row = blockIdx.x, tid = threadIdx.x;
    size_t base = (size_t)row * Dd;
    float x0 = h[base + tid], x1 = h[base + tid + 256];
    if (delta != nullptr) { x0 += delta[base + tid]; x1 += delta[base + tid + 256]; }
    red[tid] = x0 + x1; __syncthreads();
    for (int st = 128; st > 0; st >>= 1) { if (tid < st) red[tid] += red[tid + st]; __syncthreads(); }
    float m = red[0] * (1.0f / Dd); __syncthreads();
    float d0 = x0 - m, d1 = x1 - m;
    red[tid] = d0 * d0 + d1 * d1; __syncthreads();
    for (int st = 128; st > 0; st >>= 1) { if (tid < st) red[tid] += red[tid + st]; __syncthreads(); }
    float r = rsqrtf(red[0] * (1.0f / Dd) + 1e-5f);
    float y0 = d0 * r * gs[tid] + gb[tid];
    float y1 = d1 * r * gs[tid + 256] + gb[tid + 256];
    h[base + tid] = y0;         h[base + tid + 256] = y1;
    hb[base + tid] = f2b(y0);   hb[base + tid + 256] = f2b(y1);
}

extern "C" void kernel_launch(void* const* d_in, const int* in_sizes, int n_in,
                              void* d_out, int out_size, void* d_ws, size_t ws_size,
                              hipStream_t stream) {
    const int*   x     = (const int*)  d_in[0];
    const float* embed = (const float*)d_in[1];
    const float* Wq    = (const float*)d_in[2];
    const float* bq    = (const float*)d_in[3];
    const float* Wk    = (const float*)d_in[4];
    const float* bk    = (const float*)d_in[5];
    const float* Wv    = (const float*)d_in[6];
    const float* bv    = (const float*)d_in[7];
    const float* Wo    = (const float*)d_in[8];
    const float* bo    = (const float*)d_in[9];
    const float* ln1_s = (const float*)d_in[10];
    const float* ln1_b = (const float*)d_in[11];
    const float* W1    = (const float*)d_in[12];
    const float* b1    = (const float*)d_in[13];
    const float* W2    = (const float*)d_in[14];
    const float* b2    = (const float*)d_in[15];
    const float* ln2_s = (const float*)d_in[16];
    const float* ln2_b = (const float*)d_in[17];
    const float* lnf_s = (const float*)d_in[18];
    const float* lnf_b = (const float*)d_in[19];
    const float* Wl    = (const float*)d_in[20];
    const float* bl    = (const float*)d_in[21];

    // ---- workspace layout ----
    char* wp = (char*)d_ws;
    float* h    = (float*)wp;  wp += (size_t)Mtot * Dd * 4;       //  8 MB
    float* pb   = (float*)wp;  wp += (size_t)Mtot * Dd * 4;       //  8 MB
    u16*   hb   = (u16*)wp;    wp += (size_t)Mtot * Dd * 2;       //  4 MB
    u16*   qkvb = (u16*)wp;    wp += (size_t)Mtot * 1536 * 2;     // 12.6 MB
    u16*   obb  = (u16*)wp;    wp += (size_t)Mtot * Dd * 2;       //  4 MB
    u16*   fbb  = (u16*)wp;    wp += (size_t)Mtot * Ff * 2;       // 16 MB
    u16*   WlT  = (u16*)wp;    wp += (size_t)Vv * Dd * 2;         // 33 MB
    float* bqkv = (float*)wp;  wp += (size_t)Ll * 1536 * 4;       // 24 KB

    // ---- transient layer weights in d_out (dead before final logits GEMM writes it) ----
    char* op = (char*)d_out;
    u16* WqkvT = (u16*)op;  op += (size_t)Ll * 1536 * Dd * 2;
    u16* WoT   = (u16*)op;  op += (size_t)Ll * Dd * Dd * 2;
    u16* W1T   = (u16*)op;  op += (size_t)Ll * Ff * Dd * 2;
    u16* W2T   = (u16*)op;  op += (size_t)Ll * Dd * Ff * 2;

    transpose_all<<<28288, 256, 0, stream>>>(Wq, Wk, Wv, Wo, W1, W2, Wl, WqkvT, WoT, W1T, W2T, WlT);
    biaspack_kernel<<<24, 256, 0, stream>>>(bq, bk, bv, bqkv);
    embed_pe_kernel<<<(Mtot * Dd) / 256, 256, 0, stream>>>(x, embed, h, hb);

    for (int l = 0; l < Ll; l++) {
        mfma_gemm<0, 1><<<(1536 / 128) * (Mtot / 128), 256, 0, stream>>>(
            hb, WqkvT + (size_t)l * 1536 * Dd, bqkv + l * 1536, nullptr, qkvb, Mtot, 1536, Dd, 1536 / 128);
        attn_mfma<<<dim3(TT / 64, Hh, 4), 256, 0, stream>>>(qkvb, obb);
        mfma_gemm<0, 0><<<(Dd / 128) * (Mtot / 128), 256, 0, stream>>>(
            obb, WoT + (size_t)l * Dd * Dd, bo + l * Dd, pb, nullptr, Mtot, Dd, Dd, Dd / 128);
        ln_kernel<<<Mtot, 256, 0, stream>>>(h, pb, ln1_s + l * Dd, ln1_b + l * Dd, hb);
        mfma_gemm<1, 1><<<(Ff / 128) * (Mtot / 128), 256, 0, stream>>>(
            hb, W1T + (size_t)l * Ff * Dd, b1 + l * Ff, nullptr, fbb, Mtot, Ff, Dd, Ff / 128);
        mfma_gemm<0, 0><<<(Dd / 128) * (Mtot / 128), 256, 0, stream>>>(
            fbb, W2T + (size_t)l * Dd * Ff, b2 + l * Dd, pb, nullptr, Mtot, Dd, Ff, Dd / 128);
        ln_kernel<<<Mtot, 256, 0, stream>>>(h, pb, ln2_s + l * Dd, ln2_b + l * Dd, hb);
    }

    ln_kernel<<<Mtot, 256, 0, stream>>>(h, nullptr, lnf_s, lnf_b, hb);
    mfma_gemm<0, 0><<<(Vv / 128) * (Mtot / 128), 256, 0, stream>>>(
        hb, WlT, bl, (float*)d_out, nullptr, Mtot, Vv, Dd, Vv / 128);
}